// Round 2
// baseline (658.286 us; speedup 1.0000x reference)
//
#include <hip/hip_runtime.h>
#include <hip/hip_bf16.h>

#define T_ 1024
#define NB 4
#define E_ 256
#define H_ 8
#define D_ 32
#define E3 768

// ---------------------------------------------------------------------------
// Kernel A: x @ w_attn + b_attn, split q/k/v, apply RoPE to q,k.
// grid = 1024 (bn in [0,8) x 128 t-groups of 8 rows), block = 256.
// Q/K/V layout: [bh][t][d] fp32, bh = bn*8 + h.
// ---------------------------------------------------------------------------
__global__ __launch_bounds__(256) void qkv_rope_kernel(
    const float* __restrict__ x,
    const float* __restrict__ w_attn,
    const float* __restrict__ b_attn,
    float* __restrict__ Q, float* __restrict__ K, float* __restrict__ V)
{
    __shared__ float xs[8][E_];     // 8 input rows
    __shared__ float qks[8][512];   // pre-RoPE q|k rows (v needs no partner exchange)

    const int tid = threadIdx.x;
    const int blk = blockIdx.x;     // 0..1023
    const int bn  = blk >> 7;       // 0..7
    const int tg  = blk & 127;
    const int t0  = tg * 8;
    const int b   = bn >> 2, n = bn & 3;

    // stage 8 input rows (coalesced: 256 consecutive floats per row)
    #pragma unroll
    for (int r = 0; r < 8; ++r) {
        int t = t0 + r;
        xs[r][tid] = x[((size_t)(b * T_ + t) * NB + n) * E_ + tid];
    }
    __syncthreads();

    float accq[8], acck[8], accv[8];
    #pragma unroll
    for (int r = 0; r < 8; ++r) { accq[r] = 0.f; acck[r] = 0.f; accv[r] = 0.f; }

    const int j = tid;  // q col j, k col 256+j, v col 512+j
    for (int e = 0; e < E_; ++e) {
        float wq = w_attn[e * E3 + j];
        float wk = w_attn[e * E3 + 256 + j];
        float wv = w_attn[e * E3 + 512 + j];
        #pragma unroll
        for (int r = 0; r < 8; ++r) {
            float xv = xs[r][e];   // LDS broadcast
            accq[r] += xv * wq;
            acck[r] += xv * wk;
            accv[r] += xv * wv;
        }
    }
    const float bq = b_attn[j];
    const float bk = b_attn[256 + j];
    const float bv = b_attn[512 + j];
    #pragma unroll
    for (int r = 0; r < 8; ++r) {
        qks[r][j]       = accq[r] + bq;
        qks[r][256 + j] = acck[r] + bk;
    }
    __syncthreads();

    // RoPE: head h = j>>5, dim d = j&31; angle index jj = d&15; partner = j^16.
    const int h  = j >> 5, d = j & 31;
    const int jj = d & 15;
    // inv_freq = 10000^(-jj/16) = exp(-jj * ln(10000)/16)
    const float invf = __expf(-(float)jj * 0.5756462732485115f);
    const int   pj   = j ^ 16;
    const float sgn  = (d < 16) ? -1.0f : 1.0f;
    const int   bh   = bn * H_ + h;

    #pragma unroll
    for (int r = 0; r < 8; ++r) {
        int   t   = t0 + r;
        float ang = (float)t * invf;
        float s, c;
        sincosf(ang, &s, &c);   // precise version: ang up to ~1023 rad
        float qv = qks[r][j]       * c + sgn * qks[r][pj]       * s;
        float kv = qks[r][256 + j] * c + sgn * qks[r][256 + pj] * s;
        size_t base = ((size_t)bh * T_ + t) * D_ + d;
        Q[base] = qv;
        K[base] = kv;
        V[base] = accv[r] + bv;
    }
}

// ---------------------------------------------------------------------------
// Kernel B: causal flash attention, fp32. grid = (16 qtiles, 64 bh), block = 64.
// One q-row per thread: q, scores, acc all in registers; K/V tiles (32 rows)
// staged in LDS and read as wave broadcasts (conflict-free).
// O layout: [bn][t][E] fp32 (col = h*32+d).
// ---------------------------------------------------------------------------
__global__ __launch_bounds__(64) void attn_kernel(
    const float* __restrict__ Q, const float* __restrict__ K,
    const float* __restrict__ V, float* __restrict__ O)
{
    __shared__ float ks[32 * 32];
    __shared__ float vs[32 * 32];

    const int r     = threadIdx.x;      // 0..63
    const int qtile = blockIdx.x;       // 0..15
    const int bh    = blockIdx.y;       // 0..63
    const int tq    = qtile * 64 + r;

    float q[32];
    const float* Qrow = Q + ((size_t)bh * T_ + tq) * D_;
    #pragma unroll
    for (int d = 0; d < 32; d += 4) {
        float4 t4 = *(const float4*)(Qrow + d);
        q[d] = t4.x; q[d+1] = t4.y; q[d+2] = t4.z; q[d+3] = t4.w;
    }

    float m = -1e30f, l = 0.0f;
    float acc[32];
    #pragma unroll
    for (int d = 0; d < 32; ++d) acc[d] = 0.f;

    const int   ntiles = qtile * 2 + 2;          // causal: only tiles with s0 <= max tq
    const float scale  = 0.17677669529663687f;   // 1/sqrt(32)

    for (int st = 0; st < ntiles; ++st) {
        const int s0 = st * 32;
        __syncthreads();
        {   // stage K/V tile: 256 float4 each, 64 threads x 4
            const float4* Kt  = (const float4*)(K + ((size_t)bh * T_ + s0) * D_);
            const float4* Vt  = (const float4*)(V + ((size_t)bh * T_ + s0) * D_);
            float4* ks4 = (float4*)ks;
            float4* vs4 = (float4*)vs;
            #pragma unroll
            for (int i = 0; i < 4; ++i) {
                ks4[r + i * 64] = Kt[r + i * 64];
                vs4[r + i * 64] = Vt[r + i * 64];
            }
        }
        __syncthreads();

        float sc[32];
        float tm = -1e30f;
        #pragma unroll
        for (int jv = 0; jv < 32; ++jv) {
            float dot = 0.f;
            #pragma unroll
            for (int d = 0; d < 32; ++d) dot += q[d] * ks[jv * 32 + d];
            float s = (s0 + jv <= tq) ? dot * scale : -1e30f;
            sc[jv] = s;
            tm = fmaxf(tm, s);
        }
        float newm  = fmaxf(m, tm);
        float alpha = __expf(m - newm);
        l *= alpha;
        #pragma unroll
        for (int d = 0; d < 32; ++d) acc[d] *= alpha;
        #pragma unroll
        for (int jv = 0; jv < 32; ++jv) {
            float p = __expf(sc[jv] - newm);
            l += p;
            #pragma unroll
            for (int d = 0; d < 32; ++d) acc[d] += p * vs[jv * 32 + d];
        }
        m = newm;
    }

    const float inv = 1.0f / l;
    const int   bn = bh >> 3, h = bh & 7;
    float* Orow = O + ((size_t)bn * T_ + tq) * E_ + h * D_;
    #pragma unroll
    for (int d = 0; d < 32; ++d) Orow[d] = acc[d] * inv;
}

// ---------------------------------------------------------------------------
// Kernel C: O @ w_proj + b_proj, transposed store to (B,T,N,E) fp32.
// grid = 1024, block = 256.
// ---------------------------------------------------------------------------
__global__ __launch_bounds__(256) void proj_kernel(
    const float* __restrict__ O,
    const float* __restrict__ w_proj,
    const float* __restrict__ b_proj,
    float* __restrict__ out)
{
    __shared__ float os[8][E_];
    const int tid = threadIdx.x;
    const int blk = blockIdx.x;
    const int bn  = blk >> 7;
    const int tg  = blk & 127;
    const int t0  = tg * 8;
    const int b   = bn >> 2, n = bn & 3;

    #pragma unroll
    for (int r = 0; r < 8; ++r)
        os[r][tid] = O[((size_t)bn * T_ + t0 + r) * E_ + tid];
    __syncthreads();

    float acc[8];
    #pragma unroll
    for (int r = 0; r < 8; ++r) acc[r] = 0.f;

    const int c = tid;
    for (int e = 0; e < E_; ++e) {
        float wv = w_proj[e * E_ + c];
        #pragma unroll
        for (int r = 0; r < 8; ++r) acc[r] += os[r][e] * wv;
    }
    const float bp = b_proj[c];
    #pragma unroll
    for (int r = 0; r < 8; ++r) {
        int t = t0 + r;
        out[((size_t)(b * T_ + t) * NB + n) * E_ + c] = acc[r] + bp;
    }
}

// ---------------------------------------------------------------------------
extern "C" void kernel_launch(void* const* d_in, const int* in_sizes, int n_in,
                              void* d_out, int out_size, void* d_ws, size_t ws_size,
                              hipStream_t stream)
{
    const float* x      = (const float*)d_in[0];
    const float* w_attn = (const float*)d_in[1];
    const float* b_attn = (const float*)d_in[2];
    const float* w_proj = (const float*)d_in[3];
    const float* b_proj = (const float*)d_in[4];
    float* out = (float*)d_out;

    // workspace: Q,K,V each 64*1024*32 fp32; O 8*1024*256 fp32 -> 32 MB total
    float* ws = (float*)d_ws;
    float* Q = ws;
    float* K = ws + 2097152;
    float* V = ws + 4194304;
    float* O = ws + 6291456;

    qkv_rope_kernel<<<1024, 256, 0, stream>>>(x, w_attn, b_attn, Q, K, V);
    attn_kernel<<<dim3(16, 64), 64, 0, stream>>>(Q, K, V, O);
    proj_kernel<<<1024, 256, 0, stream>>>(O, w_proj, b_proj, out);
}

// Round 3
// 379.087 us; speedup vs baseline: 1.7365x; 1.7365x over previous
//
#include <hip/hip_runtime.h>
#include <hip/hip_bf16.h>

#define T_ 1024
#define NB 4
#define E_ 256
#define H_ 8
#define D_ 32
#define E3 768

// ---------------------------------------------------------------------------
// Kernel A: x @ w_attn + b_attn, split q/k/v, apply RoPE to q,k.
// 32 rows/block -> 256 blocks: cuts w_attn L2 re-read 3 GB -> 768 MB.
// RoPE partner (j^16) fetched via __shfl_xor (same wave) -- no LDS round-trip.
// Q/K/V layout: [bh][t][d] fp32, bh = bn*8 + h.
// ---------------------------------------------------------------------------
#define ROWS 32
__global__ __launch_bounds__(256) void qkv_rope_kernel(
    const float* __restrict__ x,
    const float* __restrict__ w_attn,
    const float* __restrict__ b_attn,
    float* __restrict__ Q, float* __restrict__ K, float* __restrict__ V)
{
    __shared__ float xs[ROWS][E_];

    const int tid = threadIdx.x;
    const int blk = blockIdx.x;     // 0..255
    const int bn  = blk >> 5;       // 0..7
    const int tg  = blk & 31;
    const int t0  = tg * ROWS;
    const int b   = bn >> 2, n = bn & 3;

    #pragma unroll
    for (int r = 0; r < ROWS; ++r)
        xs[r][tid] = x[((size_t)(b * T_ + t0 + r) * NB + n) * E_ + tid];
    __syncthreads();

    float accq[ROWS], acck[ROWS], accv[ROWS];
    #pragma unroll
    for (int r = 0; r < ROWS; ++r) { accq[r] = 0.f; acck[r] = 0.f; accv[r] = 0.f; }

    const int j = tid;  // q col j, k col 256+j, v col 512+j
    for (int e = 0; e < E_; ++e) {
        float wq = w_attn[e * E3 + j];
        float wk = w_attn[e * E3 + 256 + j];
        float wv = w_attn[e * E3 + 512 + j];
        #pragma unroll
        for (int r = 0; r < ROWS; ++r) {
            float xv = xs[r][e];   // LDS broadcast
            accq[r] += xv * wq;
            acck[r] += xv * wk;
            accv[r] += xv * wv;
        }
    }

    const float bq = b_attn[j];
    const float bk = b_attn[256 + j];
    const float bv = b_attn[512 + j];

    // RoPE: head h = j>>5, dim d = j&31; angle index jj = d&15; partner lane = j^16.
    const int h  = j >> 5, d = j & 31;
    const int jj = d & 15;
    const float invf = __expf(-(float)jj * 0.5756462732485115f);  // 10000^(-jj/16)
    const float sgn  = (d < 16) ? -1.0f : 1.0f;
    const int   bh   = bn * H_ + h;

    #pragma unroll
    for (int r = 0; r < ROWS; ++r) {
        float qf = accq[r] + bq;
        float kf = acck[r] + bk;
        float qp = __shfl_xor(qf, 16, 64);   // partner's full q value
        float kp = __shfl_xor(kf, 16, 64);
        int   t  = t0 + r;
        float s, c;
        sincosf((float)t * invf, &s, &c);
        float qv = qf * c + sgn * qp * s;
        float kv = kf * c + sgn * kp * s;
        size_t base = ((size_t)bh * T_ + t) * D_ + d;
        Q[base] = qv;
        K[base] = kv;
        V[base] = accv[r] + bv;
    }
}

// ---------------------------------------------------------------------------
// Kernel B: causal flash attention, fp32. grid = (16 qtiles, 64 bh), block = 256
// (4 waves). Each wave handles the SAME 64 q-rows (one per lane) but a
// round-robin subset of s-tiles (st = it*4 + wave), staged in its own private
// LDS region. Block-level merge of the 4 online-softmax partials at the end.
// O layout: [bn][t][E] fp32 (col = h*32+d).
// ---------------------------------------------------------------------------
__global__ __launch_bounds__(256) void attn_kernel(
    const float* __restrict__ Q, const float* __restrict__ K,
    const float* __restrict__ V, float* __restrict__ O)
{
    // staging: wave w uses smem[w*2048 .. w*2048+2048) (ks 1024 | vs 1024)
    // merge (after loop): macc [w][64][33] = smem[0..8448), m [w][64] at 8448,
    // l [w][64] at 8704. Total 8960 floats = 35 KB.
    __shared__ float smem[8960];

    const int tidx  = threadIdx.x;
    const int wave  = tidx >> 6;
    const int lane  = tidx & 63;
    const int qtile = blockIdx.x;       // 0..15
    const int bh    = blockIdx.y;       // 0..63
    const int tq    = qtile * 64 + lane;

    float* ks = smem + wave * 2048;
    float* vs = ks + 1024;

    float q[32];
    const float* Qrow = Q + ((size_t)bh * T_ + tq) * D_;
    #pragma unroll
    for (int d = 0; d < 32; d += 4) {
        float4 t4 = *(const float4*)(Qrow + d);
        q[d] = t4.x; q[d+1] = t4.y; q[d+2] = t4.z; q[d+3] = t4.w;
    }

    float m = -1e30f, l = 0.0f;
    float acc[32];
    #pragma unroll
    for (int d = 0; d < 32; ++d) acc[d] = 0.f;

    const int   ntiles = qtile * 2 + 2;          // causal tile count
    const int   iters  = (ntiles + 3) >> 2;      // uniform per block
    const float scale  = 0.17677669529663687f;   // 1/sqrt(32)

    for (int it = 0; it < iters; ++it) {
        const int  st     = it * 4 + wave;
        const bool active = (st < ntiles);
        if (active) {
            const int s0 = st * 32;
            const float4* Kt  = (const float4*)(K + ((size_t)bh * T_ + s0) * D_);
            const float4* Vt  = (const float4*)(V + ((size_t)bh * T_ + s0) * D_);
            float4* ks4 = (float4*)ks;
            float4* vs4 = (float4*)vs;
            #pragma unroll
            for (int i = 0; i < 4; ++i) {
                ks4[lane + i * 64] = Kt[lane + i * 64];
                vs4[lane + i * 64] = Vt[lane + i * 64];
            }
        }
        __syncthreads();   // stage -> compute visibility (wave-internal)
        if (active) {
            const int s0 = st * 32;
            float sc[32];
            float tm = -1e30f;
            #pragma unroll
            for (int jv = 0; jv < 32; ++jv) {
                float dot = 0.f;
                #pragma unroll
                for (int d = 0; d < 32; ++d) dot += q[d] * ks[jv * 32 + d];
                float s = (s0 + jv <= tq) ? dot * scale : -1e30f;
                sc[jv] = s;
                tm = fmaxf(tm, s);
            }
            float newm  = fmaxf(m, tm);
            float alpha = __expf(m - newm);
            l *= alpha;
            #pragma unroll
            for (int d = 0; d < 32; ++d) acc[d] *= alpha;
            #pragma unroll
            for (int jv = 0; jv < 32; ++jv) {
                float p = __expf(sc[jv] - newm);
                l += p;
                #pragma unroll
                for (int d = 0; d < 32; ++d) acc[d] += p * vs[jv * 32 + d];
            }
            m = newm;
        }
    }

    __syncthreads();   // all compute done before merge area overwrites staging

    float* macc = smem;          // [w][64][33] padded -> conflict-free merge reads
    float* mlm  = smem + 8448;   // [w][64]
    float* mll  = smem + 8704;   // [w][64]
    {
        float* myacc = macc + wave * 2112 + lane * 33;
        #pragma unroll
        for (int d = 0; d < 32; ++d) myacc[d] = acc[d];
        mlm[wave * 64 + lane] = m;
        mll[wave * 64 + lane] = l;
    }
    __syncthreads();

    if (wave == 0) {
        const int r = lane;
        float m0 = mlm[r], m1 = mlm[64 + r], m2 = mlm[128 + r], m3 = mlm[192 + r];
        float M = fmaxf(fmaxf(m0, m1), fmaxf(m2, m3));
        float a0 = __expf(m0 - M), a1 = __expf(m1 - M);
        float a2 = __expf(m2 - M), a3 = __expf(m3 - M);
        float L = mll[r] * a0 + mll[64 + r] * a1 + mll[128 + r] * a2 + mll[192 + r] * a3;
        float inv = 1.0f / L;
        const int bn = bh >> 3, h = bh & 7;
        float* Orow = O + ((size_t)bn * T_ + tq) * E_ + h * D_;
        #pragma unroll
        for (int d = 0; d < 32; ++d) {
            float o = macc[r * 33 + d] * a0 + macc[2112 + r * 33 + d] * a1
                    + macc[4224 + r * 33 + d] * a2 + macc[6336 + r * 33 + d] * a3;
            Orow[d] = o * inv;
        }
    }
}

// ---------------------------------------------------------------------------
// Kernel C: O @ w_proj + b_proj, transposed store to (B,T,N,E) fp32.
// grid = 1024, block = 256.
// ---------------------------------------------------------------------------
__global__ __launch_bounds__(256) void proj_kernel(
    const float* __restrict__ O,
    const float* __restrict__ w_proj,
    const float* __restrict__ b_proj,
    float* __restrict__ out)
{
    __shared__ float os[8][E_];
    const int tid = threadIdx.x;
    const int blk = blockIdx.x;
    const int bn  = blk >> 7;
    const int tg  = blk & 127;
    const int t0  = tg * 8;
    const int b   = bn >> 2, n = bn & 3;

    #pragma unroll
    for (int r = 0; r < 8; ++r)
        os[r][tid] = O[((size_t)bn * T_ + t0 + r) * E_ + tid];
    __syncthreads();

    float acc[8];
    #pragma unroll
    for (int r = 0; r < 8; ++r) acc[r] = 0.f;

    const int c = tid;
    for (int e = 0; e < E_; ++e) {
        float wv = w_proj[e * E_ + c];
        #pragma unroll
        for (int r = 0; r < 8; ++r) acc[r] += os[r][e] * wv;
    }
    const float bp = b_proj[c];
    #pragma unroll
    for (int r = 0; r < 8; ++r) {
        int t = t0 + r;
        out[((size_t)(b * T_ + t) * NB + n) * E_ + c] = acc[r] + bp;
    }
}

// ---------------------------------------------------------------------------
extern "C" void kernel_launch(void* const* d_in, const int* in_sizes, int n_in,
                              void* d_out, int out_size, void* d_ws, size_t ws_size,
                              hipStream_t stream)
{
    const float* x      = (const float*)d_in[0];
    const float* w_attn = (const float*)d_in[1];
    const float* b_attn = (const float*)d_in[2];
    const float* w_proj = (const float*)d_in[3];
    const float* b_proj = (const float*)d_in[4];
    float* out = (float*)d_out;

    // workspace: Q,K,V each 64*1024*32 fp32; O 8*1024*256 fp32 -> 32 MB total
    float* ws = (float*)d_ws;
    float* Q = ws;
    float* K = ws + 2097152;
    float* V = ws + 4194304;
    float* O = ws + 6291456;

    qkv_rope_kernel<<<256, 256, 0, stream>>>(x, w_attn, b_attn, Q, K, V);
    attn_kernel<<<dim3(16, 64), 256, 0, stream>>>(Q, K, V, O);
    proj_kernel<<<1024, 256, 0, stream>>>(O, w_proj, b_proj, out);
}

// Round 4
// 369.512 us; speedup vs baseline: 1.7815x; 1.0259x over previous
//
#include <hip/hip_runtime.h>
#include <hip/hip_bf16.h>

#define T_ 1024
#define NB 4
#define E_ 256
#define H_ 8
#define D_ 32
#define E3 768

// ---------------------------------------------------------------------------
// Kernel A: x @ w_attn + b_attn, split q/k/v, apply RoPE to q,k.
// ROWS=16 -> 512 blocks = 2 waves/SIMD (TLP to hide w-load L2 latency).
// RoPE partner (j^16) fetched via __shfl_xor (same wave).
// Q/K/V layout: [bh][t][d] fp32, bh = bn*8 + h.
// ---------------------------------------------------------------------------
#define ROWS 16
__global__ __launch_bounds__(256) void qkv_rope_kernel(
    const float* __restrict__ x,
    const float* __restrict__ w_attn,
    const float* __restrict__ b_attn,
    float* __restrict__ Q, float* __restrict__ K, float* __restrict__ V)
{
    __shared__ float xs[ROWS][E_];

    const int tid = threadIdx.x;
    const int blk = blockIdx.x;     // 0..511
    const int bn  = blk >> 6;       // 0..7
    const int tg  = blk & 63;
    const int t0  = tg * ROWS;
    const int b   = bn >> 2, n = bn & 3;

    #pragma unroll
    for (int r = 0; r < ROWS; ++r)
        xs[r][tid] = x[((size_t)(b * T_ + t0 + r) * NB + n) * E_ + tid];
    __syncthreads();

    float accq[ROWS], acck[ROWS], accv[ROWS];
    #pragma unroll
    for (int r = 0; r < ROWS; ++r) { accq[r] = 0.f; acck[r] = 0.f; accv[r] = 0.f; }

    const int j = tid;  // q col j, k col 256+j, v col 512+j
    for (int e = 0; e < E_; ++e) {
        float wq = w_attn[e * E3 + j];
        float wk = w_attn[e * E3 + 256 + j];
        float wv = w_attn[e * E3 + 512 + j];
        #pragma unroll
        for (int r = 0; r < ROWS; ++r) {
            float xv = xs[r][e];   // LDS broadcast
            accq[r] += xv * wq;
            acck[r] += xv * wk;
            accv[r] += xv * wv;
        }
    }

    const float bq = b_attn[j];
    const float bk = b_attn[256 + j];
    const float bv = b_attn[512 + j];

    // RoPE: head h = j>>5, dim d = j&31; angle index jj = d&15; partner lane = j^16.
    const int h  = j >> 5, d = j & 31;
    const int jj = d & 15;
    const float invf = __expf(-(float)jj * 0.5756462732485115f);  // 10000^(-jj/16)
    const float sgn  = (d < 16) ? -1.0f : 1.0f;
    const int   bh   = bn * H_ + h;

    #pragma unroll
    for (int r = 0; r < ROWS; ++r) {
        float qf = accq[r] + bq;
        float kf = acck[r] + bk;
        float qp = __shfl_xor(qf, 16, 64);   // partner's full q value
        float kp = __shfl_xor(kf, 16, 64);
        int   t  = t0 + r;
        float s, c;
        sincosf((float)t * invf, &s, &c);
        float qv = qf * c + sgn * qp * s;
        float kv = kf * c + sgn * kp * s;
        size_t base = ((size_t)bh * T_ + t) * D_ + d;
        Q[base] = qv;
        K[base] = kv;
        V[base] = accv[r] + bv;
    }
}

// ---------------------------------------------------------------------------
// Kernel B1: causal flash attention partials, fp32, NO LDS.
// grid = (72, 64): one wave per (bh, qtile, chunk of <=4 s-tiles). Perfectly
// balanced. K/V tile values are wave-uniform -> uniform scalar loads ride the
// scalar pipe as the SGPR operand of v_fma (no LDS, no per-FMA VMEM).
// Writes per-chunk (m, l, acc[64][32]) partials to workspace.
// ---------------------------------------------------------------------------
__global__ __launch_bounds__(64) void attn_partial_kernel(
    const float* __restrict__ Q, const float* __restrict__ K,
    const float* __restrict__ V,
    float* __restrict__ Pacc, float* __restrict__ Pm, float* __restrict__ Pl)
{
    const int lane = threadIdx.x;
    const int bh   = blockIdx.y;       // 0..63
    const int yc   = blockIdx.x;       // 0..71  -> (qtile, chunk)

    // decode (q, c): chunk counts per qtile = q/2 + 1  (sum = 72)
    int q = 0, rem = yc;
    while (rem >= (q >> 1) + 1) { rem -= (q >> 1) + 1; ++q; }
    const int c      = rem;
    const int ntiles = 2 * q + 2;
    const int tq     = q * 64 + lane;

    float qv[32];
    const float* Qrow = Q + ((size_t)bh * T_ + tq) * D_;
    #pragma unroll
    for (int d = 0; d < 32; d += 4) {
        float4 t4 = *(const float4*)(Qrow + d);
        qv[d] = t4.x; qv[d+1] = t4.y; qv[d+2] = t4.z; qv[d+3] = t4.w;
    }

    float m = -1e30f, l = 0.0f;
    float acc[32];
    #pragma unroll
    for (int d = 0; d < 32; ++d) acc[d] = 0.f;

    const float scale = 0.17677669529663687f;   // 1/sqrt(32)

    for (int t = 0; t < 4; ++t) {
        const int st = c * 4 + t;
        if (st >= ntiles) break;                // uniform
        const int s0 = st * 32;
        const float* __restrict__ Kt = K + ((size_t)bh * T_ + s0) * D_;
        const float* __restrict__ Vt = V + ((size_t)bh * T_ + s0) * D_;

        float sc[32];
        float tm = -1e30f;
        #pragma unroll
        for (int jv = 0; jv < 32; ++jv) {
            float dot = 0.f;
            #pragma unroll
            for (int d = 0; d < 32; ++d) dot += qv[d] * Kt[jv * 32 + d];  // uniform -> s_load
            float s = (s0 + jv <= tq) ? dot * scale : -1e30f;
            sc[jv] = s;
            tm = fmaxf(tm, s);
        }
        float newm  = fmaxf(m, tm);
        float alpha = __expf(m - newm);
        l *= alpha;
        #pragma unroll
        for (int d = 0; d < 32; ++d) acc[d] *= alpha;
        #pragma unroll
        for (int jv = 0; jv < 32; ++jv) {
            float p = __expf(sc[jv] - newm);
            l += p;
            #pragma unroll
            for (int d = 0; d < 32; ++d) acc[d] += p * Vt[jv * 32 + d];   // uniform -> s_load
        }
        m = newm;
    }

    const int slot = (bh * 16 + q) * 8 + c;
    float* pa = Pacc + (size_t)slot * 2048 + lane * 32;
    #pragma unroll
    for (int d = 0; d < 32; d += 4) {
        float4 t4 = { acc[d], acc[d+1], acc[d+2], acc[d+3] };
        *(float4*)(pa + d) = t4;
    }
    Pm[slot * 64 + lane] = m;
    Pl[slot * 64 + lane] = l;
}

// ---------------------------------------------------------------------------
// Kernel B2: merge <=8 chunk partials per (qtile, bh), write O.
// grid = (16, 64), block = 64 (lane = q-row).
// O layout: [bn][t][E] fp32 (col = h*32+d).
// ---------------------------------------------------------------------------
__global__ __launch_bounds__(64) void attn_merge_kernel(
    const float* __restrict__ Pacc, const float* __restrict__ Pm,
    const float* __restrict__ Pl, float* __restrict__ O)
{
    const int lane = threadIdx.x;
    const int q    = blockIdx.x;       // 0..15
    const int bh   = blockIdx.y;       // 0..63
    const int nch  = (q >> 1) + 1;
    const int base = (bh * 16 + q) * 8;

    float ms[8], ls[8];
    float M = -1e30f;
    #pragma unroll
    for (int c = 0; c < 8; ++c) {
        if (c < nch) {                                   // uniform
            ms[c] = Pm[(base + c) * 64 + lane];
            ls[c] = Pl[(base + c) * 64 + lane];
            M = fmaxf(M, ms[c]);
        }
    }

    float L = 0.f;
    float o[32];
    #pragma unroll
    for (int d = 0; d < 32; ++d) o[d] = 0.f;

    #pragma unroll
    for (int c = 0; c < 8; ++c) {
        if (c < nch) {                                   // uniform
            float a = __expf(ms[c] - M);
            L += a * ls[c];
            const float* pa = Pacc + (size_t)(base + c) * 2048 + lane * 32;
            #pragma unroll
            for (int d = 0; d < 32; d += 4) {
                float4 t4 = *(const float4*)(pa + d);
                o[d]   += a * t4.x;  o[d+1] += a * t4.y;
                o[d+2] += a * t4.z;  o[d+3] += a * t4.w;
            }
        }
    }

    const float inv = 1.0f / L;
    const int   bn = bh >> 3, h = bh & 7;
    float* Orow = O + ((size_t)bn * T_ + q * 64 + lane) * E_ + h * D_;
    #pragma unroll
    for (int d = 0; d < 32; ++d) Orow[d] = o[d] * inv;
}

// ---------------------------------------------------------------------------
// Kernel C: O @ w_proj + b_proj, transposed store to (B,T,N,E) fp32.
// grid = 1024, block = 256.
// ---------------------------------------------------------------------------
__global__ __launch_bounds__(256) void proj_kernel(
    const float* __restrict__ O,
    const float* __restrict__ w_proj,
    const float* __restrict__ b_proj,
    float* __restrict__ out)
{
    __shared__ float os[8][E_];
    const int tid = threadIdx.x;
    const int blk = blockIdx.x;
    const int bn  = blk >> 7;
    const int tg  = blk & 127;
    const int t0  = tg * 8;
    const int b   = bn >> 2, n = bn & 3;

    #pragma unroll
    for (int r = 0; r < 8; ++r)
        os[r][tid] = O[((size_t)bn * T_ + t0 + r) * E_ + tid];
    __syncthreads();

    float acc[8];
    #pragma unroll
    for (int r = 0; r < 8; ++r) acc[r] = 0.f;

    const int c = tid;
    for (int e = 0; e < E_; ++e) {
        float wv = w_proj[e * E_ + c];
        #pragma unroll
        for (int r = 0; r < 8; ++r) acc[r] += os[r][e] * wv;
    }
    const float bp = b_proj[c];
    #pragma unroll
    for (int r = 0; r < 8; ++r) {
        int t = t0 + r;
        out[((size_t)(b * T_ + t) * NB + n) * E_ + c] = acc[r] + bp;
    }
}

// ---------------------------------------------------------------------------
extern "C" void kernel_launch(void* const* d_in, const int* in_sizes, int n_in,
                              void* d_out, int out_size, void* d_ws, size_t ws_size,
                              hipStream_t stream)
{
    const float* x      = (const float*)d_in[0];
    const float* w_attn = (const float*)d_in[1];
    const float* b_attn = (const float*)d_in[2];
    const float* w_proj = (const float*)d_in[3];
    const float* b_proj = (const float*)d_in[4];
    float* out = (float*)d_out;

    // workspace (floats): Q,K,V 2M each; O 2M; Pacc 16.78M; Pm/Pl 0.5M each
    float* ws   = (float*)d_ws;
    float* Q    = ws;
    float* K    = ws + 2097152;
    float* V    = ws + 4194304;
    float* O    = ws + 6291456;
    float* Pacc = ws + 8388608;    // 8192 slots * 2048
    float* Pm   = ws + 25165824;   // 8192 * 64
    float* Pl   = ws + 25690112;   // 8192 * 64

    qkv_rope_kernel<<<512, 256, 0, stream>>>(x, w_attn, b_attn, Q, K, V);
    attn_partial_kernel<<<dim3(72, 64), 64, 0, stream>>>(Q, K, V, Pacc, Pm, Pl);
    attn_merge_kernel<<<dim3(16, 64), 64, 0, stream>>>(Pacc, Pm, Pl, O);
    proj_kernel<<<1024, 256, 0, stream>>>(O, w_proj, b_proj, out);
}

// Round 6
// 246.932 us; speedup vs baseline: 2.6659x; 1.4964x over previous
//
#include <hip/hip_runtime.h>
#include <hip/hip_bf16.h>

#define T_ 1024
#define NB 4
#define E_ 256
#define H_ 8
#define D_ 32
#define E3 768

typedef __attribute__((ext_vector_type(4))) short v4s;
typedef __attribute__((ext_vector_type(8))) short v8s;
typedef __attribute__((ext_vector_type(4))) float v4f;

// round-to-nearest-even fp32 -> bf16 bits
__device__ __forceinline__ unsigned short f2bf(float x) {
    union { float f; unsigned int u; } v; v.f = x;
    unsigned int r = v.u + 0x7fffu + ((v.u >> 16) & 1u);
    return (unsigned short)(r >> 16);
}
__device__ __forceinline__ unsigned int pack2(float lo, float hi) {
    return (unsigned int)f2bf(lo) | ((unsigned int)f2bf(hi) << 16);
}

// ---------------------------------------------------------------------------
// Kernel A: x @ w_attn + b_attn, split q/k/v, RoPE on q,k.
// Outputs bf16: Qb,Kb row-major [bh][t][d]; VT transposed [bh][d][t]
// (per-thread accv already lies along t -> packed uint4 stores, no LDS).
// ---------------------------------------------------------------------------
#define ROWS 16
__global__ __launch_bounds__(256) void qkv_rope_kernel(
    const float* __restrict__ x,
    const float* __restrict__ w_attn,
    const float* __restrict__ b_attn,
    unsigned short* __restrict__ Qb, unsigned short* __restrict__ Kb,
    unsigned short* __restrict__ VT)
{
    __shared__ float xs[ROWS][E_];

    const int tid = threadIdx.x;
    const int blk = blockIdx.x;     // 0..511
    const int bn  = blk >> 6;       // 0..7
    const int tg  = blk & 63;
    const int t0  = tg * ROWS;
    const int b   = bn >> 2, n = bn & 3;

    #pragma unroll
    for (int r = 0; r < ROWS; ++r)
        xs[r][tid] = x[((size_t)(b * T_ + t0 + r) * NB + n) * E_ + tid];
    __syncthreads();

    float accq[ROWS], acck[ROWS], accv[ROWS];
    #pragma unroll
    for (int r = 0; r < ROWS; ++r) { accq[r] = 0.f; acck[r] = 0.f; accv[r] = 0.f; }

    const int j = tid;  // q col j, k col 256+j, v col 512+j
    for (int e = 0; e < E_; ++e) {
        float wq = w_attn[e * E3 + j];
        float wk = w_attn[e * E3 + 256 + j];
        float wv = w_attn[e * E3 + 512 + j];
        #pragma unroll
        for (int r = 0; r < ROWS; ++r) {
            float xv = xs[r][e];   // LDS broadcast
            accq[r] += xv * wq;
            acck[r] += xv * wk;
            accv[r] += xv * wv;
        }
    }

    const float bq = b_attn[j];
    const float bk = b_attn[256 + j];
    const float bv = b_attn[512 + j];

    // RoPE: head h = j>>5, dim d = j&31; partner lane = j^16 (same wave).
    const int h  = j >> 5, d = j & 31;
    const int jj = d & 15;
    const float invf = __expf(-(float)jj * 0.5756462732485115f);  // 10000^(-jj/16)
    const float sgn  = (d < 16) ? -1.0f : 1.0f;
    const int   bh   = bn * H_ + h;

    float vv[ROWS];
    #pragma unroll
    for (int r = 0; r < ROWS; ++r) {
        float qf = accq[r] + bq;
        float kf = acck[r] + bk;
        float qp = __shfl_xor(qf, 16, 64);
        float kp = __shfl_xor(kf, 16, 64);
        int   t  = t0 + r;
        float s, c;
        sincosf((float)t * invf, &s, &c);
        float qv = qf * c + sgn * qp * s;
        float kv = kf * c + sgn * kp * s;
        size_t base = ((size_t)bh * T_ + t) * D_ + d;
        Qb[base] = f2bf(qv);
        Kb[base] = f2bf(kv);
        vv[r] = accv[r] + bv;
    }

    // V^T store: row d of head h, t-run [t0, t0+16) -> 2 x uint4
    unsigned int vpk[8];
    #pragma unroll
    for (int i = 0; i < 8; ++i) vpk[i] = pack2(vv[2 * i], vv[2 * i + 1]);
    unsigned short* vtp = VT + ((size_t)bh * D_ + d) * T_ + t0;
    uint4 u0 = { vpk[0], vpk[1], vpk[2], vpk[3] };
    uint4 u1 = { vpk[4], vpk[5], vpk[6], vpk[7] };
    *(uint4*)(vtp)     = u0;
    *(uint4*)(vtp + 8) = u1;
}

// ---------------------------------------------------------------------------
// Kernel B: MFMA flash attention, zero LDS. grid = (64 qtiles, 64 bh),
// block = 64 (1 wave). Wave owns 16 q-rows; iterates s-windows of 32.
// S^T = K.Q^T via mfma_f32_16x16x32_bf16 (k = full D=32): two half-tiles
// per window (s rows 0..15, 16..31). C layout: col(lane&15)=q, row(4g+r)=s.
// PV: k-index permuted so each lane's own 8 p-values form its A-frag
// (j<4 -> s0+4g+j from half A; j>=4 -> s0+16+4g+(j-4) from half B); V^T
// B-frags loaded with the same permutation (two 8B loads per VT row).
// O layout: [bn][t][E] fp32 (col = h*32+d).
// ---------------------------------------------------------------------------
__global__ __launch_bounds__(64) void attn_kernel(
    const unsigned short* __restrict__ Qb,
    const unsigned short* __restrict__ Kb,
    const unsigned short* __restrict__ VT,
    float* __restrict__ O)
{
    const int lane = threadIdx.x;
    const int g    = lane >> 4;     // 0..3
    const int c    = lane & 15;     // 0..15
    const int qt   = blockIdx.x;    // 0..63
    const int bh   = blockIdx.y;    // 0..63
    const int q0   = qt * 16;
    const int q    = q0 + c;        // this lane's softmax column

    // Q^T B-frag (held whole kernel): B[k=d=8g+j][n=q=c] -> 16B load
    v8s qfrag = *(const v8s*)(Qb + ((size_t)bh * T_ + q0 + c) * D_ + 8 * g);

    v4f oacc0 = {0.f, 0.f, 0.f, 0.f};
    v4f oacc1 = {0.f, 0.f, 0.f, 0.f};
    float m_s = -1e30f, l_s = 0.f;
    const float scale = 0.17677669529663687f;   // 1/sqrt(32)
    const int   nwin  = ((16 * qt + 15) >> 5) + 1;

    for (int w = 0; w < nwin; ++w) {
        const int s0 = w * 32;
        // K A-frags: A[m=s][k=d=8g+j], halves s0+c and s0+16+c
        v8s kfA = *(const v8s*)(Kb + ((size_t)bh * T_ + s0 + c) * D_ + 8 * g);
        v8s kfB = *(const v8s*)(Kb + ((size_t)bh * T_ + s0 + 16 + c) * D_ + 8 * g);
        // V B-frags, permuted k: elem j<4 -> s0+4g+j, j>=4 -> s0+16+4g+(j-4)
        const unsigned short* vr0 = VT + ((size_t)bh * D_ + c) * T_ + s0 + 4 * g;
        const unsigned short* vr1 = VT + ((size_t)bh * D_ + 16 + c) * T_ + s0 + 4 * g;
        v4s vlo0 = *(const v4s*)(vr0);
        v4s vhi0 = *(const v4s*)(vr0 + 16);
        v4s vlo1 = *(const v4s*)(vr1);
        v4s vhi1 = *(const v4s*)(vr1 + 16);
        v8s vf0, vf1;
        #pragma unroll
        for (int i = 0; i < 4; ++i) {
            vf0[i] = vlo0[i]; vf0[4 + i] = vhi0[i];
            vf1[i] = vlo1[i]; vf1[4 + i] = vhi1[i];
        }

        v4f zero = {0.f, 0.f, 0.f, 0.f};
        v4f sA = __builtin_amdgcn_mfma_f32_16x16x32_bf16(kfA, qfrag, zero, 0, 0, 0);
        v4f sB = __builtin_amdgcn_mfma_f32_16x16x32_bf16(kfB, qfrag, zero, 0, 0, 0);

        // softmax over s for column q=c; this lane holds 8 of 32 s-values.
        const bool last = (w == nwin - 1);
        float sv[8];
        float tmax = -1e30f;
        #pragma unroll
        for (int r = 0; r < 4; ++r) {
            float sa = sA[r] * scale;
            float sb = sB[r] * scale;
            if (last) {
                if (s0 + 4 * g + r > q)      sa = -1e30f;
                if (s0 + 16 + 4 * g + r > q) sb = -1e30f;
            }
            sv[r] = sa; sv[4 + r] = sb;
            tmax = fmaxf(tmax, fmaxf(sa, sb));
        }
        tmax = fmaxf(tmax, __shfl_xor(tmax, 16, 64));
        tmax = fmaxf(tmax, __shfl_xor(tmax, 32, 64));

        float mnew  = fmaxf(m_s, tmax);
        float alpha = __expf(m_s - mnew);
        float p[8], tsum = 0.f;
        #pragma unroll
        for (int i = 0; i < 8; ++i) { p[i] = __expf(sv[i] - mnew); tsum += p[i]; }
        tsum += __shfl_xor(tsum, 16, 64);
        tsum += __shfl_xor(tsum, 32, 64);
        l_s = l_s * alpha + tsum;
        m_s = mnew;

        // alpha lives in col domain (q=c); O rows are q=4g+r -> redistribute
        float ar[4];
        #pragma unroll
        for (int r = 0; r < 4; ++r) ar[r] = __shfl(alpha, 4 * g + r, 64);
        #pragma unroll
        for (int r = 0; r < 4; ++r) { oacc0[r] *= ar[r]; oacc1[r] *= ar[r]; }

        // P A-frag: A[m=q=c][k=8g+j] = this lane's own p[] in j order
        union { v8s v; uint4 u; } pu;
        pu.u.x = pack2(p[0], p[1]);
        pu.u.y = pack2(p[2], p[3]);
        pu.u.z = pack2(p[4], p[5]);
        pu.u.w = pack2(p[6], p[7]);
        oacc0 = __builtin_amdgcn_mfma_f32_16x16x32_bf16(pu.v, vf0, oacc0, 0, 0, 0);
        oacc1 = __builtin_amdgcn_mfma_f32_16x16x32_bf16(pu.v, vf1, oacc1, 0, 0, 0);
    }

    float linv = 1.0f / l_s;
    float lr[4];
    #pragma unroll
    for (int r = 0; r < 4; ++r) lr[r] = __shfl(linv, 4 * g + r, 64);

    const int bn = bh >> 3, h = bh & 7;
    #pragma unroll
    for (int r = 0; r < 4; ++r) {
        float* Orow = O + ((size_t)bn * T_ + q0 + 4 * g + r) * E_ + h * D_;
        Orow[c]      = oacc0[r] * lr[r];
        Orow[16 + c] = oacc1[r] * lr[r];
    }
}

// ---------------------------------------------------------------------------
// Kernel C: O @ w_proj + b_proj, transposed store to (B,T,N,E) fp32.
// grid = 1024, block = 256.
// ---------------------------------------------------------------------------
__global__ __launch_bounds__(256) void proj_kernel(
    const float* __restrict__ O,
    const float* __restrict__ w_proj,
    const float* __restrict__ b_proj,
    float* __restrict__ out)
{
    __shared__ float os[8][E_];
    const int tid = threadIdx.x;
    const int blk = blockIdx.x;
    const int bn  = blk >> 7;
    const int tg  = blk & 127;
    const int t0  = tg * 8;
    const int b   = bn >> 2, n = bn & 3;

    #pragma unroll
    for (int r = 0; r < 8; ++r)
        os[r][tid] = O[((size_t)bn * T_ + t0 + r) * E_ + tid];
    __syncthreads();

    float acc[8];
    #pragma unroll
    for (int r = 0; r < 8; ++r) acc[r] = 0.f;

    const int c = tid;
    for (int e = 0; e < E_; ++e) {
        float wv = w_proj[e * E_ + c];
        #pragma unroll
        for (int r = 0; r < 8; ++r) acc[r] += os[r][e] * wv;
    }
    const float bp = b_proj[c];
    #pragma unroll
    for (int r = 0; r < 8; ++r) {
        int t = t0 + r;
        out[((size_t)(b * T_ + t) * NB + n) * E_ + c] = acc[r] + bp;
    }
}

// ---------------------------------------------------------------------------
extern "C" void kernel_launch(void* const* d_in, const int* in_sizes, int n_in,
                              void* d_out, int out_size, void* d_ws, size_t ws_size,
                              hipStream_t stream)
{
    const float* x      = (const float*)d_in[0];
    const float* w_attn = (const float*)d_in[1];
    const float* b_attn = (const float*)d_in[2];
    const float* w_proj = (const float*)d_in[3];
    const float* b_proj = (const float*)d_in[4];
    float* out = (float*)d_out;

    // ws: Qb,Kb,VT bf16 (2M elems = 4MB each); O fp32 (2M elems = 8MB)
    unsigned short* Qb = (unsigned short*)d_ws;
    unsigned short* Kb = Qb + 2097152;
    unsigned short* VT = Kb + 2097152;
    float* O = (float*)((char*)d_ws + 12582912);

    qkv_rope_kernel<<<512, 256, 0, stream>>>(x, w_attn, b_attn, Qb, Kb, VT);
    attn_kernel<<<dim3(64, 64), 64, 0, stream>>>(Qb, Kb, VT, O);
    proj_kernel<<<1024, 256, 0, stream>>>(O, w_proj, b_proj, out);
}

// Round 7
// 187.686 us; speedup vs baseline: 3.5074x; 1.3157x over previous
//
#include <hip/hip_runtime.h>
#include <hip/hip_bf16.h>

#define T_ 1024
#define NB 4
#define E_ 256
#define H_ 8
#define D_ 32
#define E3 768

typedef __attribute__((ext_vector_type(4))) short v4s;
typedef __attribute__((ext_vector_type(8))) short v8s;
typedef __attribute__((ext_vector_type(4))) float v4f;

// round-to-nearest-even fp32 -> bf16 bits
__device__ __forceinline__ unsigned short f2bf(float x) {
    union { float f; unsigned int u; } v; v.f = x;
    unsigned int r = v.u + 0x7fffu + ((v.u >> 16) & 1u);
    return (unsigned short)(r >> 16);
}
__device__ __forceinline__ unsigned int pack2(float lo, float hi) {
    return (unsigned int)f2bf(lo) | ((unsigned int)f2bf(hi) << 16);
}

// ---------------------------------------------------------------------------
// Kernel T: fp32 [K=256][N] -> bf16 transposed [N][256]. Handles w_attn
// (bx<24) and w_proj (bx>=24) in one launch. Classic 32x33 LDS tile.
// grid (32, 8), block 256.
// ---------------------------------------------------------------------------
__global__ __launch_bounds__(256) void wtrans_kernel(
    const float* __restrict__ w_attn, const float* __restrict__ w_proj,
    unsigned short* __restrict__ WT, unsigned short* __restrict__ WPT)
{
    __shared__ float tile[32][33];
    const int bx = blockIdx.x, by = blockIdx.y;
    const float* src; unsigned short* dst; int N, n0;
    if (bx < 24) { src = w_attn; dst = WT;  N = 768; n0 = bx * 32; }
    else         { src = w_proj; dst = WPT; N = 256; n0 = (bx - 24) * 32; }
    const int k0 = by * 32;
    const int x = threadIdx.x & 31, y4 = (threadIdx.x >> 5) * 4;
    #pragma unroll
    for (int i = 0; i < 4; ++i)
        tile[y4 + i][x] = src[(size_t)(k0 + y4 + i) * N + n0 + x];
    __syncthreads();
    #pragma unroll
    for (int i = 0; i < 4; ++i)
        dst[(size_t)(n0 + y4 + i) * 256 + k0 + x] = f2bf(tile[x][y4 + i]);
}

// ---------------------------------------------------------------------------
// Kernel A: qkv = x @ w_attn + b_attn via MFMA, fused RoPE + split stores.
// grid (128, 12), block 256 (4 waves). Wave: 16 rows x 64 cols, K=256.
// Rows m = bn*1024 + t. Col block uniform type (q/k/v). RoPE partner col
// n^16 = same lane, acc[tt^1] (register-local). Outputs bf16:
// Qb,Kb [bh][t][d]; VT [bh][d][t].
// ---------------------------------------------------------------------------
__global__ __launch_bounds__(256) void qkv_mfma_kernel(
    const float* __restrict__ x,
    const float* __restrict__ b_attn,
    const unsigned short* __restrict__ WT,
    unsigned short* __restrict__ Qb, unsigned short* __restrict__ Kb,
    unsigned short* __restrict__ VT)
{
    const int tid  = threadIdx.x;
    const int wsb  = tid >> 6;
    const int lane = tid & 63;
    const int g = lane >> 4, c = lane & 15;
    const int m0 = blockIdx.x * 64 + wsb * 16;  // wave's row base (bn,t)
    const int n0 = blockIdx.y * 64;             // col base
    const int bn = m0 >> 10;                    // uniform per block
    const int b  = bn >> 2, nidx = bn & 3;
    const int t_base = m0 & 1023;

    const float* xrow = x + ((size_t)(b * T_ + t_base + c) * NB + nidx) * E_;

    v4f acc[4];
    #pragma unroll
    for (int tt = 0; tt < 4; ++tt) acc[tt] = (v4f){0.f, 0.f, 0.f, 0.f};

    #pragma unroll
    for (int k0 = 0; k0 < 256; k0 += 32) {
        float4 a0 = *(const float4*)(xrow + k0 + 8 * g);
        float4 a1 = *(const float4*)(xrow + k0 + 8 * g + 4);
        union { v8s v; uint4 u; } au;
        au.u.x = pack2(a0.x, a0.y); au.u.y = pack2(a0.z, a0.w);
        au.u.z = pack2(a1.x, a1.y); au.u.w = pack2(a1.z, a1.w);
        #pragma unroll
        for (int tt = 0; tt < 4; ++tt) {
            v8s bfrag = *(const v8s*)(WT + (size_t)(n0 + tt * 16 + c) * 256 + k0 + 8 * g);
            acc[tt] = __builtin_amdgcn_mfma_f32_16x16x32_bf16(au.v, bfrag, acc[tt], 0, 0, 0);
        }
    }

    float bias[4];
    #pragma unroll
    for (int tt = 0; tt < 4; ++tt) bias[tt] = b_attn[n0 + tt * 16 + c];

    const int type = n0 >> 8;          // 0=q 1=k 2=v (uniform per block)
    const int nl0  = n0 & 255;

    if (type <= 1) {
        unsigned short* Dst = (type == 0) ? Qb : Kb;
        const float invf = __expf(-(float)c * 0.5756462732485115f);  // 10000^(-c/16)
        float sn[4], cs[4];
        #pragma unroll
        for (int r = 0; r < 4; ++r)
            sincosf((float)(t_base + 4 * g + r) * invf, &sn[r], &cs[r]);
        #pragma unroll
        for (int tt = 0; tt < 4; ++tt) {
            const int n_l = nl0 + tt * 16;
            const int h = n_l >> 5, d = (n_l & 31) + c;
            const int bh = bn * 8 + h;
            const float sgn = (tt & 1) ? 1.f : -1.f;
            const int  ptt = tt ^ 1;
            #pragma unroll
            for (int r = 0; r < 4; ++r) {
                float v0 = acc[tt][r] + bias[tt];
                float v1 = acc[ptt][r] + bias[ptt];
                float o  = v0 * cs[r] + sgn * v1 * sn[r];
                int   t  = t_base + 4 * g + r;
                Dst[((size_t)bh * T_ + t) * D_ + d] = f2bf(o);
            }
        }
    } else {
        #pragma unroll
        for (int tt = 0; tt < 4; ++tt) {
            const int n_l = nl0 + tt * 16;
            const int h = n_l >> 5, d = (n_l & 31) + c;
            const int bh = bn * 8 + h;
            ushort4 pk;
            pk.x = f2bf(acc[tt][0] + bias[tt]);
            pk.y = f2bf(acc[tt][1] + bias[tt]);
            pk.z = f2bf(acc[tt][2] + bias[tt]);
            pk.w = f2bf(acc[tt][3] + bias[tt]);
            *(ushort4*)(VT + ((size_t)bh * D_ + d) * T_ + t_base + 4 * g) = pk;
        }
    }
}

// ---------------------------------------------------------------------------
// Kernel B: MFMA flash attention, zero LDS. grid = (64 qtiles, 64 bh),
// block = 64 (1 wave). S^T = K.Q^T via mfma_f32_16x16x32_bf16; PV with
// k-permuted frags (lane-local P). O stored bf16 [bn][t][E] (col = h*32+d).
// ---------------------------------------------------------------------------
__global__ __launch_bounds__(64) void attn_kernel(
    const unsigned short* __restrict__ Qb,
    const unsigned short* __restrict__ Kb,
    const unsigned short* __restrict__ VT,
    unsigned short* __restrict__ Ob)
{
    const int lane = threadIdx.x;
    const int g    = lane >> 4;     // 0..3
    const int c    = lane & 15;     // 0..15
    const int qt   = blockIdx.x;    // 0..63
    const int bh   = blockIdx.y;    // 0..63
    const int q0   = qt * 16;
    const int q    = q0 + c;        // this lane's softmax column

    v8s qfrag = *(const v8s*)(Qb + ((size_t)bh * T_ + q0 + c) * D_ + 8 * g);

    v4f oacc0 = {0.f, 0.f, 0.f, 0.f};
    v4f oacc1 = {0.f, 0.f, 0.f, 0.f};
    float m_s = -1e30f, l_s = 0.f;
    const float scale = 0.17677669529663687f;   // 1/sqrt(32)
    const int   nwin  = ((16 * qt + 15) >> 5) + 1;

    for (int w = 0; w < nwin; ++w) {
        const int s0 = w * 32;
        v8s kfA = *(const v8s*)(Kb + ((size_t)bh * T_ + s0 + c) * D_ + 8 * g);
        v8s kfB = *(const v8s*)(Kb + ((size_t)bh * T_ + s0 + 16 + c) * D_ + 8 * g);
        const unsigned short* vr0 = VT + ((size_t)bh * D_ + c) * T_ + s0 + 4 * g;
        const unsigned short* vr1 = VT + ((size_t)bh * D_ + 16 + c) * T_ + s0 + 4 * g;
        v4s vlo0 = *(const v4s*)(vr0);
        v4s vhi0 = *(const v4s*)(vr0 + 16);
        v4s vlo1 = *(const v4s*)(vr1);
        v4s vhi1 = *(const v4s*)(vr1 + 16);
        v8s vf0, vf1;
        #pragma unroll
        for (int i = 0; i < 4; ++i) {
            vf0[i] = vlo0[i]; vf0[4 + i] = vhi0[i];
            vf1[i] = vlo1[i]; vf1[4 + i] = vhi1[i];
        }

        v4f zero = {0.f, 0.f, 0.f, 0.f};
        v4f sA = __builtin_amdgcn_mfma_f32_16x16x32_bf16(kfA, qfrag, zero, 0, 0, 0);
        v4f sB = __builtin_amdgcn_mfma_f32_16x16x32_bf16(kfB, qfrag, zero, 0, 0, 0);

        const bool last = (w == nwin - 1);
        float sv[8];
        float tmax = -1e30f;
        #pragma unroll
        for (int r = 0; r < 4; ++r) {
            float sa = sA[r] * scale;
            float sb = sB[r] * scale;
            if (last) {
                if (s0 + 4 * g + r > q)      sa = -1e30f;
                if (s0 + 16 + 4 * g + r > q) sb = -1e30f;
            }
            sv[r] = sa; sv[4 + r] = sb;
            tmax = fmaxf(tmax, fmaxf(sa, sb));
        }
        tmax = fmaxf(tmax, __shfl_xor(tmax, 16, 64));
        tmax = fmaxf(tmax, __shfl_xor(tmax, 32, 64));

        float mnew  = fmaxf(m_s, tmax);
        float alpha = __expf(m_s - mnew);
        float p[8], tsum = 0.f;
        #pragma unroll
        for (int i = 0; i < 8; ++i) { p[i] = __expf(sv[i] - mnew); tsum += p[i]; }
        tsum += __shfl_xor(tsum, 16, 64);
        tsum += __shfl_xor(tsum, 32, 64);
        l_s = l_s * alpha + tsum;
        m_s = mnew;

        float ar[4];
        #pragma unroll
        for (int r = 0; r < 4; ++r) ar[r] = __shfl(alpha, 4 * g + r, 64);
        #pragma unroll
        for (int r = 0; r < 4; ++r) { oacc0[r] *= ar[r]; oacc1[r] *= ar[r]; }

        union { v8s v; uint4 u; } pu;
        pu.u.x = pack2(p[0], p[1]);
        pu.u.y = pack2(p[2], p[3]);
        pu.u.z = pack2(p[4], p[5]);
        pu.u.w = pack2(p[6], p[7]);
        oacc0 = __builtin_amdgcn_mfma_f32_16x16x32_bf16(pu.v, vf0, oacc0, 0, 0, 0);
        oacc1 = __builtin_amdgcn_mfma_f32_16x16x32_bf16(pu.v, vf1, oacc1, 0, 0, 0);
    }

    float linv = 1.0f / l_s;
    float lr[4];
    #pragma unroll
    for (int r = 0; r < 4; ++r) lr[r] = __shfl(linv, 4 * g + r, 64);

    const int bn = bh >> 3, h = bh & 7;
    #pragma unroll
    for (int r = 0; r < 4; ++r) {
        unsigned short* Orow = Ob + ((size_t)bn * T_ + q0 + 4 * g + r) * E_ + h * D_;
        Orow[c]      = f2bf(oacc0[r] * lr[r]);
        Orow[16 + c] = f2bf(oacc1[r] * lr[r]);
    }
}

// ---------------------------------------------------------------------------
// Kernel C: out = O @ w_proj + b_proj via MFMA, transposed fp32 store to
// (B,T,N,E). grid (128, 4), block 256 (4 waves x 16 rows x 64 cols).
// ---------------------------------------------------------------------------
__global__ __launch_bounds__(256) void proj_mfma_kernel(
    const unsigned short* __restrict__ Ob,
    const unsigned short* __restrict__ WPT,
    const float* __restrict__ b_proj,
    float* __restrict__ out)
{
    const int tid  = threadIdx.x;
    const int wsb  = tid >> 6;
    const int lane = tid & 63;
    const int g = lane >> 4, c = lane & 15;
    const int m0 = blockIdx.x * 64 + wsb * 16;
    const int n0 = blockIdx.y * 64;
    const int bn = m0 >> 10;
    const int b  = bn >> 2, nidx = bn & 3;
    const int t_base = m0 & 1023;

    const unsigned short* arow = Ob + ((size_t)bn * T_ + t_base + c) * E_;

    v4f acc[4];
    #pragma unroll
    for (int tt = 0; tt < 4; ++tt) acc[tt] = (v4f){0.f, 0.f, 0.f, 0.f};

    #pragma unroll
    for (int k0 = 0; k0 < 256; k0 += 32) {
        v8s afrag = *(const v8s*)(arow + k0 + 8 * g);
        #pragma unroll
        for (int tt = 0; tt < 4; ++tt) {
            v8s bfrag = *(const v8s*)(WPT + (size_t)(n0 + tt * 16 + c) * 256 + k0 + 8 * g);
            acc[tt] = __builtin_amdgcn_mfma_f32_16x16x32_bf16(afrag, bfrag, acc[tt], 0, 0, 0);
        }
    }

    #pragma unroll
    for (int tt = 0; tt < 4; ++tt) {
        const int n = n0 + tt * 16 + c;
        const float bp = b_proj[n];
        #pragma unroll
        for (int r = 0; r < 4; ++r) {
            const int t = t_base + 4 * g + r;
            out[((size_t)(b * T_ + t) * NB + nidx) * E_ + n] = acc[tt][r] + bp;
        }
    }
}

// ---------------------------------------------------------------------------
extern "C" void kernel_launch(void* const* d_in, const int* in_sizes, int n_in,
                              void* d_out, int out_size, void* d_ws, size_t ws_size,
                              hipStream_t stream)
{
    const float* x      = (const float*)d_in[0];
    const float* w_attn = (const float*)d_in[1];
    const float* b_attn = (const float*)d_in[2];
    const float* w_proj = (const float*)d_in[3];
    const float* b_proj = (const float*)d_in[4];
    float* out = (float*)d_out;

    // ws (ushort units): Qb/Kb/VT/Ob 2M each; WT 768*256; WPT 256*256
    unsigned short* Qb  = (unsigned short*)d_ws;
    unsigned short* Kb  = Qb + 2097152;
    unsigned short* VT  = Kb + 2097152;
    unsigned short* Ob  = VT + 2097152;
    unsigned short* WT  = Ob + 2097152;
    unsigned short* WPT = WT + 196608;

    wtrans_kernel<<<dim3(32, 8), 256, 0, stream>>>(w_attn, w_proj, WT, WPT);
    qkv_mfma_kernel<<<dim3(128, 12), 256, 0, stream>>>(x, b_attn, WT, Qb, Kb, VT);
    attn_kernel<<<dim3(64, 64), 64, 0, stream>>>(Qb, Kb, VT, Ob);
    proj_mfma_kernel<<<dim3(128, 4), 256, 0, stream>>>(Ob, WPT, b_proj, out);
}

// Round 8
// 153.489 us; speedup vs baseline: 4.2888x; 1.2228x over previous
//
#include <hip/hip_runtime.h>
#include <hip/hip_bf16.h>

#define T_ 1024
#define NB 4
#define E_ 256
#define H_ 8
#define D_ 32
#define E3 768

typedef __attribute__((ext_vector_type(4))) short v4s;
typedef __attribute__((ext_vector_type(8))) short v8s;
typedef __attribute__((ext_vector_type(4))) float v4f;

// round-to-nearest-even fp32 -> bf16 bits
__device__ __forceinline__ unsigned short f2bf(float x) {
    union { float f; unsigned int u; } v; v.f = x;
    unsigned int r = v.u + 0x7fffu + ((v.u >> 16) & 1u);
    return (unsigned short)(r >> 16);
}
__device__ __forceinline__ unsigned int pack2(float lo, float hi) {
    return (unsigned int)f2bf(lo) | ((unsigned int)f2bf(hi) << 16);
}

// ---------------------------------------------------------------------------
// Kernel T: fp32 [K=256][N] -> bf16 transposed [N][256]. Handles w_attn
// (bx<24) and w_proj (bx>=24) in one launch. Classic 32x33 LDS tile.
// grid (32, 8), block 256.
// ---------------------------------------------------------------------------
__global__ __launch_bounds__(256) void wtrans_kernel(
    const float* __restrict__ w_attn, const float* __restrict__ w_proj,
    unsigned short* __restrict__ WT, unsigned short* __restrict__ WPT)
{
    __shared__ float tile[32][33];
    const int bx = blockIdx.x, by = blockIdx.y;
    const float* src; unsigned short* dst; int N, n0;
    if (bx < 24) { src = w_attn; dst = WT;  N = 768; n0 = bx * 32; }
    else         { src = w_proj; dst = WPT; N = 256; n0 = (bx - 24) * 32; }
    const int k0 = by * 32;
    const int x = threadIdx.x & 31, y4 = (threadIdx.x >> 5) * 4;
    #pragma unroll
    for (int i = 0; i < 4; ++i)
        tile[y4 + i][x] = src[(size_t)(k0 + y4 + i) * N + n0 + x];
    __syncthreads();
    #pragma unroll
    for (int i = 0; i < 4; ++i)
        dst[(size_t)(n0 + y4 + i) * 256 + k0 + x] = f2bf(tile[x][y4 + i]);
}

// ---------------------------------------------------------------------------
// Kernel A: qkv = x @ w_attn + b_attn via MFMA, fused RoPE + split stores.
// grid (128, 12), block 256 (4 waves). Wave: 16 rows x 64 cols, K=256.
// RoPE partner col n^16 = same lane, acc[tt^1] (register-local).
// Outputs bf16: Qb,Kb [bh][t][d]; VT [bh][d][t].
// ---------------------------------------------------------------------------
__global__ __launch_bounds__(256) void qkv_mfma_kernel(
    const float* __restrict__ x,
    const float* __restrict__ b_attn,
    const unsigned short* __restrict__ WT,
    unsigned short* __restrict__ Qb, unsigned short* __restrict__ Kb,
    unsigned short* __restrict__ VT)
{
    const int tid  = threadIdx.x;
    const int wsb  = tid >> 6;
    const int lane = tid & 63;
    const int g = lane >> 4, c = lane & 15;
    const int m0 = blockIdx.x * 64 + wsb * 16;  // wave's row base (bn,t)
    const int n0 = blockIdx.y * 64;             // col base
    const int bn = m0 >> 10;                    // uniform per block
    const int b  = bn >> 2, nidx = bn & 3;
    const int t_base = m0 & 1023;

    const float* xrow = x + ((size_t)(b * T_ + t_base + c) * NB + nidx) * E_;

    v4f acc[4];
    #pragma unroll
    for (int tt = 0; tt < 4; ++tt) acc[tt] = (v4f){0.f, 0.f, 0.f, 0.f};

    #pragma unroll
    for (int k0 = 0; k0 < 256; k0 += 32) {
        float4 a0 = *(const float4*)(xrow + k0 + 8 * g);
        float4 a1 = *(const float4*)(xrow + k0 + 8 * g + 4);
        union { v8s v; uint4 u; } au;
        au.u.x = pack2(a0.x, a0.y); au.u.y = pack2(a0.z, a0.w);
        au.u.z = pack2(a1.x, a1.y); au.u.w = pack2(a1.z, a1.w);
        #pragma unroll
        for (int tt = 0; tt < 4; ++tt) {
            v8s bfrag = *(const v8s*)(WT + (size_t)(n0 + tt * 16 + c) * 256 + k0 + 8 * g);
            acc[tt] = __builtin_amdgcn_mfma_f32_16x16x32_bf16(au.v, bfrag, acc[tt], 0, 0, 0);
        }
    }

    float bias[4];
    #pragma unroll
    for (int tt = 0; tt < 4; ++tt) bias[tt] = b_attn[n0 + tt * 16 + c];

    const int type = n0 >> 8;          // 0=q 1=k 2=v (uniform per block)
    const int nl0  = n0 & 255;

    if (type <= 1) {
        unsigned short* Dst = (type == 0) ? Qb : Kb;
        const float invf = __expf(-(float)c * 0.5756462732485115f);  // 10000^(-c/16)
        float sn[4], cs[4];
        #pragma unroll
        for (int r = 0; r < 4; ++r)
            sincosf((float)(t_base + 4 * g + r) * invf, &sn[r], &cs[r]);
        #pragma unroll
        for (int tt = 0; tt < 4; ++tt) {
            const int n_l = nl0 + tt * 16;
            const int h = n_l >> 5, d = (n_l & 31) + c;
            const int bh = bn * 8 + h;
            const float sgn = (tt & 1) ? 1.f : -1.f;
            const int  ptt = tt ^ 1;
            #pragma unroll
            for (int r = 0; r < 4; ++r) {
                float v0 = acc[tt][r] + bias[tt];
                float v1 = acc[ptt][r] + bias[ptt];
                float o  = v0 * cs[r] + sgn * v1 * sn[r];
                int   t  = t_base + 4 * g + r;
                Dst[((size_t)bh * T_ + t) * D_ + d] = f2bf(o);
            }
        }
    } else {
        #pragma unroll
        for (int tt = 0; tt < 4; ++tt) {
            const int n_l = nl0 + tt * 16;
            const int h = n_l >> 5, d = (n_l & 31) + c;
            const int bh = bn * 8 + h;
            ushort4 pk;
            pk.x = f2bf(acc[tt][0] + bias[tt]);
            pk.y = f2bf(acc[tt][1] + bias[tt]);
            pk.z = f2bf(acc[tt][2] + bias[tt]);
            pk.w = f2bf(acc[tt][3] + bias[tt]);
            *(ushort4*)(VT + ((size_t)bh * D_ + d) * T_ + t_base + 4 * g) = pk;
        }
    }
}

// ---------------------------------------------------------------------------
// Kernel B: MFMA flash attention, zero LDS, software-pipelined K/V loads.
// One qtile pass: wave owns 16 q-rows, iterates s-windows of 32 with
// next-window fragments prefetched (clamped address, branch-free) so load
// latency overlaps the softmax/MFMA chain of the current window.
// ---------------------------------------------------------------------------
__device__ __forceinline__ void attn_one_qtile(
    const int qt, const int bh, const int lane,
    const unsigned short* __restrict__ Qb,
    const unsigned short* __restrict__ Kb,
    const unsigned short* __restrict__ VT,
    unsigned short* __restrict__ Ob)
{
    const int g  = lane >> 4;      // 0..3
    const int c  = lane & 15;      // 0..15
    const int q0 = qt * 16;
    const int q  = q0 + c;         // this lane's softmax column

    const unsigned short* Kbase = Kb + (size_t)bh * T_ * D_;
    const unsigned short* Vb0   = VT + ((size_t)bh * D_ + c) * T_;
    const unsigned short* Vb1   = VT + ((size_t)bh * D_ + 16 + c) * T_;

    v8s qfrag = *(const v8s*)(Qb + ((size_t)bh * T_ + q0 + c) * D_ + 8 * g);

    const int nwin  = (qt >> 1) + 1;
    const int slast = (nwin - 1) * 32;

    // preload window 0
    v8s kfA  = *(const v8s*)(Kbase + (size_t)c * D_ + 8 * g);
    v8s kfB  = *(const v8s*)(Kbase + (size_t)(16 + c) * D_ + 8 * g);
    v4s vlo0 = *(const v4s*)(Vb0 + 4 * g);
    v4s vhi0 = *(const v4s*)(Vb0 + 16 + 4 * g);
    v4s vlo1 = *(const v4s*)(Vb1 + 4 * g);
    v4s vhi1 = *(const v4s*)(Vb1 + 16 + 4 * g);

    v4f oacc0 = {0.f, 0.f, 0.f, 0.f};
    v4f oacc1 = {0.f, 0.f, 0.f, 0.f};
    float m_s = -1e30f, l_s = 0.f;
    const float scale = 0.17677669529663687f;   // 1/sqrt(32)

    for (int w = 0; w < nwin; ++w) {
        const int s0 = w * 32;
        // prefetch next window (clamped -> always valid, branch-free)
        const int sn = (s0 + 32 <= slast) ? s0 + 32 : slast;
        v8s nkfA  = *(const v8s*)(Kbase + (size_t)(sn + c) * D_ + 8 * g);
        v8s nkfB  = *(const v8s*)(Kbase + (size_t)(sn + 16 + c) * D_ + 8 * g);
        v4s nvlo0 = *(const v4s*)(Vb0 + sn + 4 * g);
        v4s nvhi0 = *(const v4s*)(Vb0 + sn + 16 + 4 * g);
        v4s nvlo1 = *(const v4s*)(Vb1 + sn + 4 * g);
        v4s nvhi1 = *(const v4s*)(Vb1 + sn + 16 + 4 * g);

        // V B-frags, permuted k: elem j<4 -> s0+4g+j, j>=4 -> s0+16+4g+(j-4)
        v8s vf0, vf1;
        #pragma unroll
        for (int i = 0; i < 4; ++i) {
            vf0[i] = vlo0[i]; vf0[4 + i] = vhi0[i];
            vf1[i] = vlo1[i]; vf1[4 + i] = vhi1[i];
        }

        v4f zero = {0.f, 0.f, 0.f, 0.f};
        v4f sA = __builtin_amdgcn_mfma_f32_16x16x32_bf16(kfA, qfrag, zero, 0, 0, 0);
        v4f sB = __builtin_amdgcn_mfma_f32_16x16x32_bf16(kfB, qfrag, zero, 0, 0, 0);

        const bool last = (w == nwin - 1);
        float sv[8];
        float tmax = -1e30f;
        #pragma unroll
        for (int r = 0; r < 4; ++r) {
            float sa = sA[r] * scale;
            float sb = sB[r] * scale;
            if (last) {
                if (s0 + 4 * g + r > q)      sa = -1e30f;
                if (s0 + 16 + 4 * g + r > q) sb = -1e30f;
            }
            sv[r] = sa; sv[4 + r] = sb;
            tmax = fmaxf(tmax, fmaxf(sa, sb));
        }
        tmax = fmaxf(tmax, __shfl_xor(tmax, 16, 64));
        tmax = fmaxf(tmax, __shfl_xor(tmax, 32, 64));

        float mnew  = fmaxf(m_s, tmax);
        float alpha = __expf(m_s - mnew);
        float p[8], tsum = 0.f;
        #pragma unroll
        for (int i = 0; i < 8; ++i) { p[i] = __expf(sv[i] - mnew); tsum += p[i]; }
        tsum += __shfl_xor(tsum, 16, 64);
        tsum += __shfl_xor(tsum, 32, 64);
        l_s = l_s * alpha + tsum;
        m_s = mnew;

        // alpha lives in col domain (q=c); O rows are q=4g+r -> redistribute
        float ar[4];
        #pragma unroll
        for (int r = 0; r < 4; ++r) ar[r] = __shfl(alpha, 4 * g + r, 64);
        #pragma unroll
        for (int r = 0; r < 4; ++r) { oacc0[r] *= ar[r]; oacc1[r] *= ar[r]; }

        // P A-frag: A[m=q=c][k=8g+j] = this lane's own p[] in j order
        union { v8s v; uint4 u; } pu;
        pu.u.x = pack2(p[0], p[1]);
        pu.u.y = pack2(p[2], p[3]);
        pu.u.z = pack2(p[4], p[5]);
        pu.u.w = pack2(p[6], p[7]);
        oacc0 = __builtin_amdgcn_mfma_f32_16x16x32_bf16(pu.v, vf0, oacc0, 0, 0, 0);
        oacc1 = __builtin_amdgcn_mfma_f32_16x16x32_bf16(pu.v, vf1, oacc1, 0, 0, 0);

        kfA = nkfA; kfB = nkfB;
        vlo0 = nvlo0; vhi0 = nvhi0; vlo1 = nvlo1; vhi1 = nvhi1;
    }

    float linv = 1.0f / l_s;
    float lr[4];
    #pragma unroll
    for (int r = 0; r < 4; ++r) lr[r] = __shfl(linv, 4 * g + r, 64);

    const int bn = bh >> 3, h = bh & 7;
    #pragma unroll
    for (int r = 0; r < 4; ++r) {
        unsigned short* Orow = Ob + ((size_t)bn * T_ + q0 + 4 * g + r) * E_ + h * D_;
        Orow[c]      = f2bf(oacc0[r] * lr[r]);
        Orow[16 + c] = f2bf(oacc1[r] * lr[r]);
    }
}

// grid = (32, 64), block = 64. Each block handles the balanced qtile pair
// (bx, 63-bx): every block does exactly 33 windows -> no straggler tail.
__global__ __launch_bounds__(64) void attn_kernel(
    const unsigned short* __restrict__ Qb,
    const unsigned short* __restrict__ Kb,
    const unsigned short* __restrict__ VT,
    unsigned short* __restrict__ Ob)
{
    const int lane = threadIdx.x;
    const int bx   = blockIdx.x;    // 0..31
    const int bh   = blockIdx.y;    // 0..63
    attn_one_qtile(bx, bh, lane, Qb, Kb, VT, Ob);
    attn_one_qtile(63 - bx, bh, lane, Qb, Kb, VT, Ob);
}

// ---------------------------------------------------------------------------
// Kernel C: out = O @ w_proj + b_proj via MFMA, transposed fp32 store to
// (B,T,N,E). grid (128, 4), block 256 (4 waves x 16 rows x 64 cols).
// ---------------------------------------------------------------------------
__global__ __launch_bounds__(256) void proj_mfma_kernel(
    const unsigned short* __restrict__ Ob,
    const unsigned short* __restrict__ WPT,
    const float* __restrict__ b_proj,
    float* __restrict__ out)
{
    const int tid  = threadIdx.x;
    const int wsb  = tid >> 6;
    const int lane = tid & 63;
    const int g = lane >> 4, c = lane & 15;
    const int m0 = blockIdx.x * 64 + wsb * 16;
    const int n0 = blockIdx.y * 64;
    const int bn = m0 >> 10;
    const int b  = bn >> 2, nidx = bn & 3;
    const int t_base = m0 & 1023;

    const unsigned short* arow = Ob + ((size_t)bn * T_ + t_base + c) * E_;

    v4f acc[4];
    #pragma unroll
    for (int tt = 0; tt < 4; ++tt) acc[tt] = (v4f){0.f, 0.f, 0.f, 0.f};

    #pragma unroll
    for (int k0 = 0; k0 < 256; k0 += 32) {
        v8s afrag = *(const v8s*)(arow + k0 + 8 * g);
        #pragma unroll
        for (int tt = 0; tt < 4; ++tt) {
            v8s bfrag = *(const v8s*)(WPT + (size_t)(n0 + tt * 16 + c) * 256 + k0 + 8 * g);
            acc[tt] = __builtin_amdgcn_mfma_f32_16x16x32_bf16(afrag, bfrag, acc[tt], 0, 0, 0);
        }
    }

    #pragma unroll
    for (int tt = 0; tt < 4; ++tt) {
        const int n = n0 + tt * 16 + c;
        const float bp = b_proj[n];
        #pragma unroll
        for (int r = 0; r < 4; ++r) {
            const int t = t_base + 4 * g + r;
            out[((size_t)(b * T_ + t) * NB + nidx) * E_ + n] = acc[tt][r] + bp;
        }
    }
}

// ---------------------------------------------------------------------------
extern "C" void kernel_launch(void* const* d_in, const int* in_sizes, int n_in,
                              void* d_out, int out_size, void* d_ws, size_t ws_size,
                              hipStream_t stream)
{
    const float* x      = (const float*)d_in[0];
    const float* w_attn = (const float*)d_in[1];
    const float* b_attn = (const float*)d_in[2];
    const float* w_proj = (const float*)d_in[3];
    const float* b_proj = (const float*)d_in[4];
    float* out = (float*)d_out;

    // ws (ushort units): Qb/Kb/VT/Ob 2M each; WT 768*256; WPT 256*256
    unsigned short* Qb  = (unsigned short*)d_ws;
    unsigned short* Kb  = Qb + 2097152;
    unsigned short* VT  = Kb + 2097152;
    unsigned short* Ob  = VT + 2097152;
    unsigned short* WT  = Ob + 2097152;
    unsigned short* WPT = WT + 196608;

    wtrans_kernel<<<dim3(32, 8), 256, 0, stream>>>(w_attn, w_proj, WT, WPT);
    qkv_mfma_kernel<<<dim3(128, 12), 256, 0, stream>>>(x, b_attn, WT, Qb, Kb, VT);
    attn_kernel<<<dim3(32, 64), 64, 0, stream>>>(Qb, Kb, VT, Ob);
    proj_mfma_kernel<<<dim3(128, 4), 256, 0, stream>>>(Ob, WPT, b_proj, out);
}